// Round 1
// baseline (1216.699 us; speedup 1.0000x reference)
//
#include <hip/hip_runtime.h>

// GAT conv: N=100000 nodes, E=1.6M edges, IN_C=128, OUT_C=32, HEADS=4 (OC=128)
// Decomposition:
//   x_proj = x @ W.T                      (GEMM, fp32 vector ALU)
//   l[n,h] = <x_proj[n,h,:], att_l[h,:]>  r[n,h] = <x_proj[n,h,:], att_r[h,:]>
//   alpha_e,h = exp(leaky(l[row]+r[col]));  denom[n,h] = scatter-sum
//   out[n,h,:] = (1/denom) * scatter-sum alpha * x_proj[col,h,:]  + bias

constexpr float NEG_SLOPE = 0.2f;

__global__ __launch_bounds__(256) void k_transpose_w(const float* __restrict__ W,
                                                     float* __restrict__ Wt) {
    int i = blockIdx.x * 256 + threadIdx.x;
    if (i < 128 * 128) {
        int o = i >> 7, k = i & 127;
        Wt[k * 128 + o] = W[i];
    }
}

// 64 nodes per block, 256 threads; thread (tx,ty) computes 8 nodes x 4 outputs.
// x tile in LDS (32KB); Wt read coalesced from global (64KB, L1/L2 resident).
__global__ __launch_bounds__(256) void k_gemm(const float* __restrict__ x,
                                              const float* __restrict__ Wt,
                                              float* __restrict__ xp, int N) {
    __shared__ float xs[64 * 128];
    int t = threadIdx.x;
    int nb = blockIdx.x * 64;
    const float4* x4 = (const float4*)x;
    float4* xs4 = (float4*)xs;
#pragma unroll
    for (int m = 0; m < 8; ++m) {
        int idx = t + 256 * m;           // 0..2047 float4 slots
        int nl = idx >> 5, kk = idx & 31;
        int n = nb + nl;
        float4 v = make_float4(0.f, 0.f, 0.f, 0.f);
        if (n < N) v = x4[(size_t)n * 32 + kk];
        xs4[idx] = v;
    }
    __syncthreads();
    int tx = t & 31, ty = t >> 5;   // tx: o-lane (32), ty: n-group (8)
    float acc[8][4];
#pragma unroll
    for (int i = 0; i < 8; ++i)
#pragma unroll
        for (int j = 0; j < 4; ++j) acc[i][j] = 0.f;
#pragma unroll 4
    for (int k = 0; k < 128; ++k) {
        float w0 = Wt[k * 128 + tx];
        float w1 = Wt[k * 128 + tx + 32];
        float w2 = Wt[k * 128 + tx + 64];
        float w3 = Wt[k * 128 + tx + 96];
#pragma unroll
        for (int i = 0; i < 8; ++i) {
            float xk = xs[(ty * 8 + i) * 128 + k];  // 2-way broadcast: free
            acc[i][0] += xk * w0;
            acc[i][1] += xk * w1;
            acc[i][2] += xk * w2;
            acc[i][3] += xk * w3;
        }
    }
#pragma unroll
    for (int i = 0; i < 8; ++i) {
        int n = nb + ty * 8 + i;
        if (n < N) {
#pragma unroll
            for (int j = 0; j < 4; ++j)
                xp[(size_t)n * 128 + tx + 32 * j] = acc[i][j];
        }
    }
}

// One thread per (n,h): l = <x_proj[n,h,:], att_l[h,:]>, r likewise.
__global__ __launch_bounds__(256) void k_lr(const float* __restrict__ xp,
                                            const float* __restrict__ attl,
                                            const float* __restrict__ attr,
                                            float* __restrict__ l, float* __restrict__ r,
                                            int N) {
    int gid = blockIdx.x * 256 + threadIdx.x;
    if (gid >= N * 4) return;
    int h = gid & 3;
    const float4* rowp = (const float4*)xp + (size_t)(gid >> 2) * 32 + h * 8;
    const float4* al = (const float4*)attl + h * 8;
    const float4* ar = (const float4*)attr + h * 8;
    float dl = 0.f, dr = 0.f;
#pragma unroll
    for (int q = 0; q < 8; ++q) {
        float4 v = rowp[q];
        float4 a = al[q];
        float4 b = ar[q];
        dl += v.x * a.x + v.y * a.y + v.z * a.z + v.w * a.w;
        dr += v.x * b.x + v.y * b.y + v.z * b.z + v.w * b.w;
    }
    l[gid] = dl;
    r[gid] = dr;
}

// One thread per edge: 4 atomics into denom[row,h].
__global__ __launch_bounds__(256) void k_denom(const int* __restrict__ ei,
                                               const float* __restrict__ l,
                                               const float* __restrict__ r,
                                               float* __restrict__ denom, int E) {
    int e = blockIdx.x * 256 + threadIdx.x;
    if (e >= E) return;
    int row = ei[e], col = ei[E + e];
    float4 lv = ((const float4*)l)[row];
    float4 rv = ((const float4*)r)[col];
    float a0 = lv.x + rv.x, a1 = lv.y + rv.y, a2 = lv.z + rv.z, a3 = lv.w + rv.w;
    a0 = a0 >= 0.f ? a0 : NEG_SLOPE * a0;
    a1 = a1 >= 0.f ? a1 : NEG_SLOPE * a1;
    a2 = a2 >= 0.f ? a2 : NEG_SLOPE * a2;
    a3 = a3 >= 0.f ? a3 : NEG_SLOPE * a3;
    atomicAdd(&denom[row * 4 + 0], __expf(a0));
    atomicAdd(&denom[row * 4 + 1], __expf(a1));
    atomicAdd(&denom[row * 4 + 2], __expf(a2));
    atomicAdd(&denom[row * 4 + 3], __expf(a3));
}

// 128 threads per edge (2 edges / 256-block): gather x_proj[col], scale by
// unnormalized alpha, scatter-add into out[row]. Normalization deferred.
__global__ __launch_bounds__(256) void k_scatter(const int* __restrict__ ei,
                                                 const float* __restrict__ l,
                                                 const float* __restrict__ r,
                                                 const float* __restrict__ xp,
                                                 float* __restrict__ out, int E) {
    int local = threadIdx.x >> 7;
    int e = blockIdx.x * 2 + local;
    if (e >= E) return;
    int c = threadIdx.x & 127;
    int h = c >> 5;
    int row = ei[e], col = ei[E + e];
    float a = l[row * 4 + h] + r[col * 4 + h];
    a = a >= 0.f ? a : NEG_SLOPE * a;
    float w = __expf(a);
    float val = w * xp[(size_t)col * 128 + c];
    atomicAdd(&out[(size_t)row * 128 + c], val);
}

__global__ __launch_bounds__(256) void k_final(float* __restrict__ out,
                                               const float* __restrict__ denom,
                                               const float* __restrict__ bias, int N) {
    int i = blockIdx.x * 256 + threadIdx.x;
    if (i >= N * 128) return;
    int n = i >> 7;
    int h = (i >> 5) & 3;
    out[i] = out[i] / (denom[n * 4 + h] + 1e-16f) + bias[i & 127];
}

extern "C" void kernel_launch(void* const* d_in, const int* in_sizes, int n_in,
                              void* d_out, int out_size, void* d_ws, size_t ws_size,
                              hipStream_t stream) {
    const float* x    = (const float*)d_in[0];
    const int*   ei   = (const int*)d_in[1];
    const float* W    = (const float*)d_in[2];
    const float* attl = (const float*)d_in[3];
    const float* attr = (const float*)d_in[4];
    const float* bias = (const float*)d_in[5];
    int N = in_sizes[0] / 128;
    int E = in_sizes[1] / 2;

    float* ws    = (float*)d_ws;
    float* xp    = ws;                       // N*128 floats (51.2 MB)
    float* l     = xp + (size_t)N * 128;     // N*4
    float* r     = l + (size_t)N * 4;        // N*4
    float* denom = r + (size_t)N * 4;        // N*4
    float* Wt    = denom + (size_t)N * 4;    // 128*128

    float* out = (float*)d_out;

    hipMemsetAsync(out, 0, (size_t)out_size * sizeof(float), stream);
    hipMemsetAsync(denom, 0, (size_t)N * 4 * sizeof(float), stream);

    k_transpose_w<<<64, 256, 0, stream>>>(W, Wt);
    k_gemm<<<(N + 63) / 64, 256, 0, stream>>>(x, Wt, xp, N);
    k_lr<<<(N * 4 + 255) / 256, 256, 0, stream>>>(xp, attl, attr, l, r, N);
    k_denom<<<(E + 255) / 256, 256, 0, stream>>>(ei, l, r, denom, E);
    k_scatter<<<(E + 1) / 2, 256, 0, stream>>>(ei, l, r, xp, out, E);
    k_final<<<(N * 128 + 255) / 256, 256, 0, stream>>>(out, denom, bias, N);
}

// Round 2
// 508.666 us; speedup vs baseline: 2.3919x; 2.3919x over previous
//
#include <hip/hip_runtime.h>

// GAT conv: N=100000 nodes, E=1.6M edges, IN_C=128, OUT_C=32, HEADS=4 (OC=128)
// Round 2: replace atomic scatter (691us, atomic-RMW bound, 800MB HBM writes)
// with CSR-by-row + one-wave-per-row register accumulation. Denominator and
// final normalize/bias are fused into the row pass (w depends only on head,
// so denom accumulates per-lane with no cross-lane reduction until one
// shfl_xor(32) at the end).

constexpr float NEG_SLOPE = 0.2f;

__global__ __launch_bounds__(256) void k_transpose_w(const float* __restrict__ W,
                                                     float* __restrict__ Wt) {
    int i = blockIdx.x * 256 + threadIdx.x;
    if (i < 128 * 128) {
        int o = i >> 7, k = i & 127;
        Wt[k * 128 + o] = W[i];
    }
}

// 64 nodes per block, 256 threads; thread (tx,ty) computes 8 nodes x 4 outputs.
__global__ __launch_bounds__(256) void k_gemm(const float* __restrict__ x,
                                              const float* __restrict__ Wt,
                                              float* __restrict__ xp, int N) {
    __shared__ float xs[64 * 128];
    int t = threadIdx.x;
    int nb = blockIdx.x * 64;
    const float4* x4 = (const float4*)x;
    float4* xs4 = (float4*)xs;
#pragma unroll
    for (int m = 0; m < 8; ++m) {
        int idx = t + 256 * m;
        int nl = idx >> 5, kk = idx & 31;
        int n = nb + nl;
        float4 v = make_float4(0.f, 0.f, 0.f, 0.f);
        if (n < N) v = x4[(size_t)n * 32 + kk];
        xs4[idx] = v;
    }
    __syncthreads();
    int tx = t & 31, ty = t >> 5;
    float acc[8][4];
#pragma unroll
    for (int i = 0; i < 8; ++i)
#pragma unroll
        for (int j = 0; j < 4; ++j) acc[i][j] = 0.f;
#pragma unroll 4
    for (int k = 0; k < 128; ++k) {
        float w0 = Wt[k * 128 + tx];
        float w1 = Wt[k * 128 + tx + 32];
        float w2 = Wt[k * 128 + tx + 64];
        float w3 = Wt[k * 128 + tx + 96];
#pragma unroll
        for (int i = 0; i < 8; ++i) {
            float xk = xs[(ty * 8 + i) * 128 + k];
            acc[i][0] += xk * w0;
            acc[i][1] += xk * w1;
            acc[i][2] += xk * w2;
            acc[i][3] += xk * w3;
        }
    }
#pragma unroll
    for (int i = 0; i < 8; ++i) {
        int n = nb + ty * 8 + i;
        if (n < N) {
#pragma unroll
            for (int j = 0; j < 4; ++j)
                xp[(size_t)n * 128 + tx + 32 * j] = acc[i][j];
        }
    }
}

// One thread per (n,h): l = <x_proj[n,h,:], att_l[h,:]>, r likewise.
__global__ __launch_bounds__(256) void k_lr(const float* __restrict__ xp,
                                            const float* __restrict__ attl,
                                            const float* __restrict__ attr,
                                            float* __restrict__ l, float* __restrict__ r,
                                            int N) {
    int gid = blockIdx.x * 256 + threadIdx.x;
    if (gid >= N * 4) return;
    int h = gid & 3;
    const float4* rowp = (const float4*)xp + (size_t)(gid >> 2) * 32 + h * 8;
    const float4* al = (const float4*)attl + h * 8;
    const float4* ar = (const float4*)attr + h * 8;
    float dl = 0.f, dr = 0.f;
#pragma unroll
    for (int q = 0; q < 8; ++q) {
        float4 v = rowp[q];
        float4 a = al[q];
        float4 b = ar[q];
        dl += v.x * a.x + v.y * a.y + v.z * a.z + v.w * a.w;
        dr += v.x * b.x + v.y * b.y + v.z * b.z + v.w * b.w;
    }
    l[gid] = dl;
    r[gid] = dr;
}

// ---- CSR build ----
__global__ __launch_bounds__(256) void k_hist(const int* __restrict__ ei,
                                              int* __restrict__ counts, int E) {
    int e = blockIdx.x * 256 + threadIdx.x;
    if (e < E) atomicAdd(&counts[ei[e]], 1);
}

// Block scans 2048 counts (256 thr x 8); writes exclusive partials in-place
// semantics into `part`, block totals into bsum.
__global__ __launch_bounds__(256) void k_scan1(const int* __restrict__ counts,
                                               int* __restrict__ part,
                                               int* __restrict__ bsum, int N) {
    __shared__ int sdata[256];
    int base = blockIdx.x * 2048;
    int t = threadIdx.x;
    int v[8];
    int s = 0;
#pragma unroll
    for (int j = 0; j < 8; ++j) {
        int idx = base + t * 8 + j;
        v[j] = (idx < N) ? counts[idx] : 0;
        s += v[j];
    }
    sdata[t] = s;
    __syncthreads();
    for (int off = 1; off < 256; off <<= 1) {
        int val = (t >= off) ? sdata[t - off] : 0;
        __syncthreads();
        sdata[t] += val;
        __syncthreads();
    }
    int run = (t == 0) ? 0 : sdata[t - 1];
    if (t == 255) bsum[blockIdx.x] = sdata[255];
#pragma unroll
    for (int j = 0; j < 8; ++j) {
        int idx = base + t * 8 + j;
        if (idx < N) part[idx] = run;
        run += v[j];
    }
}

__global__ void k_scan2(int* __restrict__ bsum, int nb) {
    if (threadIdx.x == 0 && blockIdx.x == 0) {
        int run = 0;
        for (int i = 0; i < nb; ++i) {
            int c = bsum[i];
            bsum[i] = run;
            run += c;
        }
    }
}

// row_ptr[i] = part[i] + bsum[i>>11] (in place on part); cursor copy for fill.
__global__ __launch_bounds__(256) void k_scan3(int* __restrict__ part,
                                               const int* __restrict__ bsum,
                                               int* __restrict__ cursor, int N) {
    int i = blockIdx.x * 256 + threadIdx.x;
    if (i < N) {
        int v = part[i] + bsum[i >> 11];
        part[i] = v;
        cursor[i] = v;
    }
}

__global__ __launch_bounds__(256) void k_fill(const int* __restrict__ ei,
                                              int* __restrict__ cursor,
                                              int* __restrict__ ecol, int E) {
    int e = blockIdx.x * 256 + threadIdx.x;
    if (e >= E) return;
    int row = ei[e], col = ei[E + e];
    int pos = atomicAdd(&cursor[row], 1);
    ecol[pos] = col;
}

// One wave per row. Lane layout: li = lane&31 covers channels 4*li..4*li+3
// (float4); half = lane>>5 processes even/odd edges. Denominator per lane
// (depends only on head h = li>>3). One shfl_xor(32) combine at the end.
__global__ __launch_bounds__(256) void k_rowpass(const int* __restrict__ row_ptr,
                                                 const int* __restrict__ counts,
                                                 const int* __restrict__ ecol,
                                                 const float* __restrict__ l,
                                                 const float* __restrict__ r,
                                                 const float* __restrict__ xp,
                                                 const float* __restrict__ bias,
                                                 float* __restrict__ out, int N) {
    int wid = (blockIdx.x * 256 + threadIdx.x) >> 6;
    if (wid >= N) return;
    int lane = threadIdx.x & 63;
    int half = lane >> 5;
    int li = lane & 31;
    int h = li >> 3;
    int row = wid;
    int start = row_ptr[row];
    int deg = counts[row];
    float lh = l[row * 4 + h];
    const float4* xp4 = (const float4*)xp;
    float4 acc = make_float4(0.f, 0.f, 0.f, 0.f);
    float dsum = 0.f;
#pragma unroll 2
    for (int i = half; i < deg; i += 2) {
        int col = ecol[start + i];
        float a = lh + r[col * 4 + h];
        a = a >= 0.f ? a : NEG_SLOPE * a;
        float w = __expf(a);
        float4 xv = xp4[(size_t)col * 32 + li];
        acc.x += w * xv.x;
        acc.y += w * xv.y;
        acc.z += w * xv.z;
        acc.w += w * xv.w;
        dsum += w;
    }
    acc.x += __shfl_xor(acc.x, 32);
    acc.y += __shfl_xor(acc.y, 32);
    acc.z += __shfl_xor(acc.z, 32);
    acc.w += __shfl_xor(acc.w, 32);
    dsum += __shfl_xor(dsum, 32);
    if (half == 0) {
        float inv = 1.f / (dsum + 1e-16f);
        float4 b = ((const float4*)bias)[li];
        float4 o;
        o.x = acc.x * inv + b.x;
        o.y = acc.y * inv + b.y;
        o.z = acc.z * inv + b.z;
        o.w = acc.w * inv + b.w;
        ((float4*)out)[(size_t)row * 32 + li] = o;
    }
}

extern "C" void kernel_launch(void* const* d_in, const int* in_sizes, int n_in,
                              void* d_out, int out_size, void* d_ws, size_t ws_size,
                              hipStream_t stream) {
    const float* x    = (const float*)d_in[0];
    const int*   ei   = (const int*)d_in[1];
    const float* W    = (const float*)d_in[2];
    const float* attl = (const float*)d_in[3];
    const float* attr = (const float*)d_in[4];
    const float* bias = (const float*)d_in[5];
    int N = in_sizes[0] / 128;
    int E = in_sizes[1] / 2;

    char* ws = (char*)d_ws;
    float* xp     = (float*)ws;                 ws += (size_t)N * 128 * 4;  // 51.2 MB
    float* l      = (float*)ws;                 ws += (size_t)N * 4 * 4;
    float* r      = (float*)ws;                 ws += (size_t)N * 4 * 4;
    float* Wt     = (float*)ws;                 ws += 128 * 128 * 4;
    int*   counts = (int*)ws;                   ws += (size_t)N * 4;
    int*   rowptr = (int*)ws;                   ws += (size_t)N * 4;        // = part, scanned in place
    int*   cursor = (int*)ws;                   ws += (size_t)N * 4;
    int*   bsum   = (int*)ws;                   ws += 256 * 4;
    int*   ecol   = (int*)ws;                   ws += (size_t)E * 4;        // 6.4 MB

    float* out = (float*)d_out;

    hipMemsetAsync(counts, 0, (size_t)N * sizeof(int), stream);

    int nscan = (N + 2047) / 2048;
    k_transpose_w<<<64, 256, 0, stream>>>(W, Wt);
    k_hist<<<(E + 255) / 256, 256, 0, stream>>>(ei, counts, E);
    k_gemm<<<(N + 63) / 64, 256, 0, stream>>>(x, Wt, xp, N);
    k_lr<<<(N * 4 + 255) / 256, 256, 0, stream>>>(xp, attl, attr, l, r, N);
    k_scan1<<<nscan, 256, 0, stream>>>(counts, rowptr, bsum, N);
    k_scan2<<<1, 64, 0, stream>>>(bsum, nscan);
    k_scan3<<<(N + 255) / 256, 256, 0, stream>>>(rowptr, bsum, cursor, N);
    k_fill<<<(E + 255) / 256, 256, 0, stream>>>(ei, cursor, ecol, E);
    k_rowpass<<<(N + 3) / 4, 256, 0, stream>>>(rowptr, counts, ecol, l, r, xp, bias, out, N);
}